// Round 3
// baseline (653.302 us; speedup 1.0000x reference)
//
#include <hip/hip_runtime.h>
#include <hip/hip_bf16.h>

constexpr int N_NODES = 100000;
constexpr int N_REL   = 4;
constexpr int N_EDGES = 600000;
constexpr int MAXDEG  = 32;          // Poisson(6): P(deg>=32) ~ 7e-14 per node
constexpr int D       = 128;
constexpr int KTOT    = N_REL * D;   // 512 concat cols of A
constexpr int M_PAD   = 100096;      // 782 blocks * 128 rows
constexpr int NSLC    = 8;           // XCD column slices (16 cols = 32B each)

// ---- bucketed-build geometry ----
constexpr int NB   = 128;            // buckets per relation
constexpr int BW   = 784;            // node width per bucket (128*784 = 100352 >= 100000)
constexpr int NKEY = N_REL * NB;     // 512 (r,bucket) keys
constexpr int CAP  = 5632;           // per-bucket capacity: mu=4704, sigma=68 -> +13.6 sigma
constexpr int EPB  = 2048;           // edges per pass-1 block (256 thr x 8)
constexpr int TOT_E   = N_REL * N_EDGES;            // 2.4M
constexpr int P1_BLKS = (TOT_E + EPB - 1) / EPB;    // 1172
constexpr int XC_BLKS = (N_NODES * D / 4) / 256;    // 12500
constexpr int WC_BLKS = (N_REL * D * D) / 256;      // 256

typedef __attribute__((ext_vector_type(8))) short bf16x8;   // MFMA A/B frag (4 VGPRs)
typedef __attribute__((ext_vector_type(4))) float f32x4;    // MFMA C/D frag

static __device__ __forceinline__ unsigned short f2bf(float f) {
    union { float f; unsigned int u; } v; v.f = f;
    unsigned int r = (v.u + 0x7fffu + ((v.u >> 16) & 1u)) >> 16;  // RNE
    return (unsigned short)r;
}

// ---------------------------------------------------------------------------
// 1) Pass 1: bucket-scatter edges by dst (8B) and src (4B) into 512 coarse
//    buckets each, via block-local LDS histograms + one range-reservation
//    atomic per (block,bucket). Cast blocks ride along. Wt is built with the
//    sliced K-permutation j = s*64 + (c16>>1)*8 + r*2 + (c16&1), matching
//    the gather's A layout (GEMM is permutation-invariant when both match).
// ---------------------------------------------------------------------------
__global__ __launch_bounds__(256) void pass1(const int* __restrict__ edges,
                                             int* __restrict__ gcur,        // [2*NKEY*16] padded counters
                                             uint2* __restrict__ bktd,      // [NKEY*CAP] (src,dst)
                                             unsigned* __restrict__ bkts,   // [NKEY*CAP] src only
                                             const float* __restrict__ X,
                                             unsigned short* __restrict__ Xb,
                                             const float* __restrict__ W,
                                             unsigned short* __restrict__ Wt) {
    int b = blockIdx.x;
    if (b < P1_BLKS) {
        __shared__ int hd[NKEY], hs[NKEY], bd[NKEY], bs[NKEY];
        int tid = threadIdx.x;
        for (int k = tid; k < NKEY; k += 256) { hd[k] = 0; hs[k] = 0; }
        __syncthreads();

        int e0 = b * EPB;
        int src[8], dst[8], kd[8], ks[8];
#pragma unroll
        for (int k = 0; k < 8; k++) {
            int t = e0 + k * 256 + tid;
            kd[k] = -1; ks[k] = -1; src[k] = 0; dst[k] = 0;
            if (t < TOT_E) {
                int r = t / N_EDGES;
                int e = t - r * N_EDGES;
                src[k] = edges[(size_t)(r * 2)     * N_EDGES + e];
                dst[k] = edges[(size_t)(r * 2 + 1) * N_EDGES + e];
                kd[k] = r * NB + dst[k] / BW;
                ks[k] = r * NB + src[k] / BW;
                atomicAdd(&hd[kd[k]], 1);
                atomicAdd(&hs[ks[k]], 1);
            }
        }
        __syncthreads();
        for (int k = tid; k < NKEY; k += 256) {
            int c = hd[k];
            bd[k] = c ? atomicAdd(&gcur[k * 16], c) : 0;
            hd[k] = 0;                       // reuse as local rank counter
            c = hs[k];
            bs[k] = c ? atomicAdd(&gcur[(NKEY + k) * 16], c) : 0;
            hs[k] = 0;
        }
        __syncthreads();
#pragma unroll
        for (int k = 0; k < 8; k++) {
            if (kd[k] >= 0) {
                int p = bd[kd[k]] + atomicAdd(&hd[kd[k]], 1);
                if (p < CAP) bktd[(size_t)kd[k] * CAP + p] = make_uint2((unsigned)src[k], (unsigned)dst[k]);
                p = bs[ks[k]] + atomicAdd(&hs[ks[k]], 1);
                if (p < CAP) bkts[(size_t)ks[k] * CAP + p] = (unsigned)src[k];
            }
        }
    } else if (b < P1_BLKS + XC_BLKS) {
        int t = (b - P1_BLKS) * 256 + threadIdx.x;
        float4 v = ((const float4*)X)[t];
        union { unsigned short u[4]; uint2 d; } o;
        o.u[0] = f2bf(v.x); o.u[1] = f2bf(v.y); o.u[2] = f2bf(v.z); o.u[3] = f2bf(v.w);
        ((uint2*)Xb)[t] = o.d;
    } else {
        int t = (b - P1_BLKS - XC_BLKS) * 256 + threadIdx.x;
        int r = t >> 14;
        int k = (t >> 7) & 127;
        int n = t & 127;
        int s   = k >> 4;                    // slice
        int c16 = k & 15;                    // col within slice
        int j   = s * 64 + (c16 >> 1) * 8 + r * 2 + (c16 & 1);
        Wt[(size_t)n * KTOT + j] = f2bf(W[t]);
    }
}

// ---------------------------------------------------------------------------
// 2a) out-degree histogram -> rsqrt table (must finish before pass2b embeds c)
// ---------------------------------------------------------------------------
__global__ __launch_bounds__(1024) void pass2a(const int* __restrict__ gcur,
                                               const unsigned* __restrict__ bkts,
                                               float* __restrict__ routf) {
    __shared__ int cur[BW];
    int b = blockIdx.x, tid = threadIdx.x;
    if (tid < BW) cur[tid] = 0;
    __syncthreads();
    int r = b >> 7;
    int node0 = (b & 127) * BW;
    int cnt = min(gcur[(NKEY + b) * 16], CAP);
    for (int i = tid; i < cnt; i += 1024)
        atomicAdd(&cur[(int)bkts[(size_t)b * CAP + i] - node0], 1);
    __syncthreads();
    int nN = min(BW, N_NODES - node0);
    if (tid < nN) {
        int c = cur[tid];
        routf[r * N_NODES + node0 + tid] = rsqrtf((float)(c < 1 ? 1 : c));
    }
}

// ---------------------------------------------------------------------------
// 2b) ELL fill with LDS cursors; each slot stores (src, c=rout[src]) as uint2
//     so the gather's per-slice staging is a pure coalesced stream.
// ---------------------------------------------------------------------------
__global__ __launch_bounds__(1024) void pass2b(const int* __restrict__ gcur,
                                               const uint2* __restrict__ bktd,
                                               const float* __restrict__ routf,
                                               uint2* __restrict__ esrcc,
                                               int* __restrict__ indeg) {
    __shared__ int cur[BW];
    int b = blockIdx.x, tid = threadIdx.x;
    if (tid < BW) cur[tid] = 0;
    __syncthreads();
    int r = b >> 7;
    int node0 = (b & 127) * BW;
    int cnt = min(gcur[b * 16], CAP);
    for (int i = tid; i < cnt; i += 1024) {
        uint2 ed = bktd[(size_t)b * CAP + i];
        int pos = atomicAdd(&cur[(int)ed.y - node0], 1);
        if (pos < MAXDEG) {
            union { float f; unsigned u; } c; c.f = routf[r * N_NODES + (int)ed.x];
            esrcc[((size_t)r * N_NODES + (int)ed.y) * MAXDEG + pos] = make_uint2(ed.x, c.u);
        }
    }
    __syncthreads();
    int nN = min(BW, N_NODES - node0);
    if (tid < nN) indeg[r * N_NODES + node0 + tid] = cur[tid];
}

// ---------------------------------------------------------------------------
// 3) XCD-sliced gather: slice = blockIdx & 7 -> under modular round-robin
//    dispatch, each 16-col slice of Xb (3.2 MB) is private to one XCD's L2.
//    Wave = 8 nodes x 8 lanes, branchless; (src,c) staged once per block
//    into LDS; inactive slots load row 0 (L1-hot) with c=0.
// ---------------------------------------------------------------------------
__global__ __launch_bounds__(256) void gather_sliced(const uint2* __restrict__ esrcc,
                                                     const int* __restrict__ indeg,
                                                     const unsigned* __restrict__ Xv,
                                                     uint4* __restrict__ A4) {
    __shared__ uint2 meta[N_REL][MAXDEG][32];  // [r][slot][node] 32KB
    __shared__ float rinl[N_REL][32];
    __shared__ short nds[N_REL][32];
    __shared__ int   nmx[4];
    int tid = threadIdx.x;
    int s     = blockIdx.x & 7;
    int node0 = (blockIdx.x >> 3) * 32;

    if (tid < 4) nmx[tid] = 0;
    __syncthreads();
    if (tid < 128) {
        int node = tid & 31, r = tid >> 5;
        int ind = indeg[r * N_NODES + node0 + node];
        int n = ind > MAXDEG ? MAXDEG : ind;
        nds[r][node]  = (short)n;
        rinl[r][node] = rsqrtf((float)(ind < 1 ? 1 : ind));
        atomicMax(&nmx[node >> 3], n);
    }
    __syncthreads();
    for (int idx = tid; idx < 4096; idx += 256) {
        int slot = idx & 31, r = (idx >> 5) & 3, node = idx >> 7;
        uint2 m = make_uint2(0u, 0u);
        if (slot < (int)nds[r][node])
            m = esrcc[((size_t)r * N_NODES + node0 + node) * MAXDEG + slot];
        meta[r][slot][node] = m;
    }
    __syncthreads();

    int node = tid >> 3;
    int l7   = tid & 7;
    int nmax = nmx[node >> 3];
    const unsigned* Xp = Xv + (size_t)s * 8 + l7;   // col pair (s*16 + 2*l7, +1)

    float2 acc[N_REL];
#pragma unroll
    for (int r = 0; r < N_REL; r++) acc[r] = make_float2(0.f, 0.f);

#pragma unroll 4
    for (int i = 0; i < nmax; i++) {
        uint2 m[N_REL];
#pragma unroll
        for (int r = 0; r < N_REL; r++) m[r] = meta[r][i][node];
        unsigned v[N_REL];
#pragma unroll
        for (int r = 0; r < N_REL; r++) v[r] = Xp[(size_t)m[r].x * (D / 2)];
#pragma unroll
        for (int r = 0; r < N_REL; r++) {
            union { unsigned u; float f; } cc; cc.u = m[r].y;
            union { unsigned u; float f; } lo, hi;
            lo.u = v[r] << 16;
            hi.u = v[r] & 0xFFFF0000u;
            acc[r].x += cc.f * lo.f;
            acc[r].y += cc.f * hi.f;
        }
    }

    unsigned o[N_REL];
#pragma unroll
    for (int r = 0; r < N_REL; r++) {
        float ri = rinl[r][node];
        o[r] = (unsigned)f2bf(ri * acc[r].x) | ((unsigned)f2bf(ri * acc[r].y) << 16);
    }
    A4[(size_t)(node0 + node) * (KTOT / 8) + s * 8 + l7] = make_uint4(o[0], o[1], o[2], o[3]);
}

// ---------------------------------------------------------------------------
// 4) Final GEMM: Z[100K][128] = A[100K][512](bf16) @ Wt^T via 16x16x32 MFMA.
//    A and Wt share the sliced K-permutation -> result unchanged.
// ---------------------------------------------------------------------------
__global__ __launch_bounds__(256) void gemm_mfma(const unsigned short* __restrict__ A,
                                                 const unsigned short* __restrict__ Wt,
                                                 float* __restrict__ Z) {
    int w    = threadIdx.x >> 6;
    int lane = threadIdx.x & 63;
    int l15  = lane & 15;
    int quad = lane >> 4;
    int row0 = blockIdx.x * 128 + w * 32;

    f32x4 acc[2][8];
#pragma unroll
    for (int m = 0; m < 2; m++)
#pragma unroll
        for (int j = 0; j < 8; j++) acc[m][j] = (f32x4){0.f, 0.f, 0.f, 0.f};

    for (int k0 = 0; k0 < KTOT; k0 += 32) {
        bf16x8 a[2];
#pragma unroll
        for (int m = 0; m < 2; m++)
            a[m] = *(const bf16x8*)(A + (size_t)(row0 + m * 16 + l15) * KTOT + k0 + quad * 8);
#pragma unroll
        for (int j = 0; j < 8; j++) {
            bf16x8 b = *(const bf16x8*)(Wt + (size_t)(j * 16 + l15) * KTOT + k0 + quad * 8);
            acc[0][j] = __builtin_amdgcn_mfma_f32_16x16x32_bf16(a[0], b, acc[0][j], 0, 0, 0);
            acc[1][j] = __builtin_amdgcn_mfma_f32_16x16x32_bf16(a[1], b, acc[1][j], 0, 0, 0);
        }
    }

    // C/D layout: col = lane&15, row = quad*4 + reg
#pragma unroll
    for (int m = 0; m < 2; m++)
#pragma unroll
        for (int reg = 0; reg < 4; reg++) {
            int row = row0 + m * 16 + quad * 4 + reg;
            if (row < N_NODES) {
#pragma unroll
                for (int j = 0; j < 8; j++)
                    Z[(size_t)row * D + j * 16 + l15] = acc[m][j][reg];
            }
        }
}

// ---------------------------------------------------------------------------
extern "C" void kernel_launch(void* const* d_in, const int* in_sizes, int n_in,
                              void* d_out, int out_size, void* d_ws, size_t ws_size,
                              hipStream_t stream) {
    const int*   edges = (const int*)d_in[0];
    const float* X     = (const float*)d_in[1];
    const float* W     = (const float*)d_in[2];
    float*       Z     = (float*)d_out;

    auto align256 = [](size_t x) { return (x + 255) & ~(size_t)255; };
    char* ws = (char*)d_ws;
    size_t off = 0;
    int* gcur          = (int*)(ws + off);            off = align256(off + (size_t)2 * NKEY * 16 * sizeof(int));
    int* indeg         = (int*)(ws + off);            off = align256(off + (size_t)N_REL * N_NODES * sizeof(int));
    float* routf       = (float*)(ws + off);          off = align256(off + (size_t)N_REL * N_NODES * sizeof(float));
    uint2* esrcc       = (uint2*)(ws + off);          off = align256(off + (size_t)N_REL * N_NODES * MAXDEG * sizeof(uint2));
    unsigned short* Xb = (unsigned short*)(ws + off); off = align256(off + (size_t)N_NODES * D * sizeof(short));
    unsigned short* Wt = (unsigned short*)(ws + off); off = align256(off + (size_t)KTOT * D * sizeof(short));
    unsigned short* A  = (unsigned short*)(ws + off); off = align256(off + (size_t)M_PAD * KTOT * sizeof(short));
    // bucket arrays overlay A's region: dead before gather writes A.
    uint2*    bktd = (uint2*)A;                                    // NKEY*CAP*8B = 23.1 MB
    unsigned* bkts = (unsigned*)((char*)A + (size_t)NKEY * CAP * sizeof(uint2));  // +11.5 MB

    // only the 64 KB padded range-reservation counters need zeroing
    hipMemsetAsync(gcur, 0, (size_t)2 * NKEY * 16 * sizeof(int), stream);

    pass1<<<P1_BLKS + XC_BLKS + WC_BLKS, 256, 0, stream>>>(
        edges, gcur, bktd, bkts, X, Xb, W, Wt);

    pass2a<<<NKEY, 1024, 0, stream>>>(gcur, bkts, routf);

    pass2b<<<NKEY, 1024, 0, stream>>>(gcur, bktd, routf, esrcc, indeg);

    gather_sliced<<<NSLC * (N_NODES / 32), 256, 0, stream>>>(
        esrcc, indeg, (const unsigned*)Xb, (uint4*)A);

    gemm_mfma<<<M_PAD / 128, 256, 0, stream>>>(A, Wt, Z);
}

// Round 4
// 363.620 us; speedup vs baseline: 1.7967x; 1.7967x over previous
//
#include <hip/hip_runtime.h>
#include <hip/hip_bf16.h>

constexpr int N_NODES = 100000;
constexpr int N_REL   = 4;
constexpr int N_EDGES = 600000;
constexpr int MAXDEG  = 32;          // Poisson(6): P(deg>=32) ~ 7e-14 per node
constexpr int D       = 128;
constexpr int KTOT    = N_REL * D;   // 512 concat cols of A
constexpr int M_PAD   = 100096;      // 782 blocks * 128 rows

// ---- bucketed-build geometry ----
constexpr int NB   = 128;            // buckets per relation
constexpr int BW   = 784;            // node width per bucket (128*784 = 100352 >= 100000)
constexpr int NKEY = N_REL * NB;     // 512 (r,bucket) keys
constexpr int CAP  = 5632;           // per-bucket capacity: mu=4704, sigma=68 -> +13.6 sigma
constexpr int EPB  = 2048;           // edges per pass-1 block (256 thr x 8)
constexpr int TOT_E   = N_REL * N_EDGES;            // 2.4M
constexpr int P1_BLKS = (TOT_E + EPB - 1) / EPB;    // 1172
constexpr int XC_BLKS = (N_NODES * D / 4) / 256;    // 12500
constexpr int WC_BLKS = (N_REL * D * D) / 256;      // 256

typedef __attribute__((ext_vector_type(8))) short bf16x8;   // MFMA A/B frag (4 VGPRs)
typedef __attribute__((ext_vector_type(4))) float f32x4;    // MFMA C/D frag

static __device__ __forceinline__ unsigned short f2bf(float f) {
    union { float f; unsigned int u; } v; v.f = f;
    unsigned int r = (v.u + 0x7fffu + ((v.u >> 16) & 1u)) >> 16;  // RNE
    return (unsigned short)r;
}

// ---------------------------------------------------------------------------
// 1) Pass 1: bucket-scatter edges by dst (packed 4B: src|dstloc<<17) and src
//    (4B) into 512 coarse buckets each, via block-local LDS histograms + one
//    range-reservation atomic per (block,bucket). Cast blocks ride along.
// ---------------------------------------------------------------------------
__global__ __launch_bounds__(256) void pass1(const int* __restrict__ edges,
                                             int* __restrict__ gcur,        // [2*NKEY*16] padded counters
                                             unsigned* __restrict__ bktd,   // [NKEY*CAP] packed (src,dstloc)
                                             unsigned* __restrict__ bkts,   // [NKEY*CAP] src only
                                             const float* __restrict__ X,
                                             unsigned short* __restrict__ Xb,
                                             const float* __restrict__ W,
                                             unsigned short* __restrict__ Wt) {
    int b = blockIdx.x;
    if (b < P1_BLKS) {
        __shared__ int hd[NKEY], hs[NKEY], bd[NKEY], bs[NKEY];
        int tid = threadIdx.x;
        for (int k = tid; k < NKEY; k += 256) { hd[k] = 0; hs[k] = 0; }
        __syncthreads();

        int e0 = b * EPB;
        int src[8], dst[8], kd[8], ks[8];
#pragma unroll
        for (int k = 0; k < 8; k++) {
            int t = e0 + k * 256 + tid;
            kd[k] = -1; ks[k] = -1; src[k] = 0; dst[k] = 0;
            if (t < TOT_E) {
                int r = t / N_EDGES;
                int e = t - r * N_EDGES;
                src[k] = edges[(size_t)(r * 2)     * N_EDGES + e];
                dst[k] = edges[(size_t)(r * 2 + 1) * N_EDGES + e];
                kd[k] = r * NB + dst[k] / BW;
                ks[k] = r * NB + src[k] / BW;
                atomicAdd(&hd[kd[k]], 1);
                atomicAdd(&hs[ks[k]], 1);
            }
        }
        __syncthreads();
        for (int k = tid; k < NKEY; k += 256) {
            int c = hd[k];
            bd[k] = c ? atomicAdd(&gcur[k * 16], c) : 0;
            hd[k] = 0;                       // reuse as local rank counter
            c = hs[k];
            bs[k] = c ? atomicAdd(&gcur[(NKEY + k) * 16], c) : 0;
            hs[k] = 0;
        }
        __syncthreads();
#pragma unroll
        for (int k = 0; k < 8; k++) {
            if (kd[k] >= 0) {
                int dstloc = dst[k] - (kd[k] - (kd[k] >> 7) * NB) * BW;   // dst - bucket*BW
                int p = bd[kd[k]] + atomicAdd(&hd[kd[k]], 1);
                if (p < CAP) bktd[(size_t)kd[k] * CAP + p] = (unsigned)src[k] | ((unsigned)dstloc << 17);
                p = bs[ks[k]] + atomicAdd(&hs[ks[k]], 1);
                if (p < CAP) bkts[(size_t)ks[k] * CAP + p] = (unsigned)src[k];
            }
        }
    } else if (b < P1_BLKS + XC_BLKS) {
        int t = (b - P1_BLKS) * 256 + threadIdx.x;
        float4 v = ((const float4*)X)[t];
        union { unsigned short u[4]; uint2 d; } o;
        o.u[0] = f2bf(v.x); o.u[1] = f2bf(v.y); o.u[2] = f2bf(v.z); o.u[3] = f2bf(v.w);
        ((uint2*)Xb)[t] = o.d;
    } else {
        int t = (b - P1_BLKS - XC_BLKS) * 256 + threadIdx.x;
        int r = t >> 14;
        int k = (t >> 7) & 127;
        int n = t & 127;
        Wt[(size_t)n * KTOT + r * D + k] = f2bf(W[t]);
    }
}

// ---------------------------------------------------------------------------
// 2a) src-bucket histogram -> rsqrt(outdeg) table (needed before 2b embeds c)
// ---------------------------------------------------------------------------
__global__ __launch_bounds__(1024) void pass2a(const int* __restrict__ gcur,
                                               const unsigned* __restrict__ bkts,
                                               float* __restrict__ routf) {
    __shared__ int cur[BW];
    int b = blockIdx.x, tid = threadIdx.x;
    if (tid < BW) cur[tid] = 0;
    __syncthreads();
    int r = b >> 7;
    int node0 = (b & 127) * BW;
    int cnt = min(gcur[(NKEY + b) * 16], CAP);
    for (int i = tid; i < cnt; i += 1024)
        atomicAdd(&cur[(int)bkts[(size_t)b * CAP + i] - node0], 1);
    __syncthreads();
    int nN = min(BW, N_NODES - node0);
    if (tid < nN) {
        int c = cur[tid];
        routf[r * N_NODES + node0 + tid] = rsqrtf((float)(c < 1 ? 1 : c));
    }
}

// ---------------------------------------------------------------------------
// 2b) ELL fill with LDS cursors; each slot stores (src, c=rout[src]) as uint2
//     so the gather's staging is a pure coalesced stream (no random lookups).
//     routf random reads here are L2-hot (1.6 MB) and hide under the scatter.
// ---------------------------------------------------------------------------
__global__ __launch_bounds__(1024) void pass2b(const int* __restrict__ gcur,
                                               const unsigned* __restrict__ bktd,
                                               const float* __restrict__ routf,
                                               uint2* __restrict__ esrcc,
                                               int* __restrict__ indeg) {
    __shared__ int cur[BW];
    int b = blockIdx.x, tid = threadIdx.x;
    if (tid < BW) cur[tid] = 0;
    __syncthreads();
    int r = b >> 7;
    int node0 = (b & 127) * BW;
    int cnt = min(gcur[b * 16], CAP);
    for (int i = tid; i < cnt; i += 1024) {
        unsigned rec = bktd[(size_t)b * CAP + i];
        int s      = (int)(rec & 0x1FFFFu);
        int dstloc = (int)(rec >> 17);
        int pos = atomicAdd(&cur[dstloc], 1);
        if (pos < MAXDEG) {
            union { float f; unsigned u; } c; c.f = routf[r * N_NODES + s];
            esrcc[((size_t)r * N_NODES + node0 + dstloc) * MAXDEG + pos] = make_uint2((unsigned)s, c.u);
        }
    }
    __syncthreads();
    int nN = min(BW, N_NODES - node0);
    if (tid < nN) indeg[r * N_NODES + node0 + tid] = cur[tid];
}

// ---------------------------------------------------------------------------
// 3) Fused 4-relation gather (round-2 structure): two dst nodes per wave,
//    32 lanes x 8B row loads. Staging now streams pre-built (src,c) pairs --
//    no random routf/outdeg lookups. Branchless inner loop; inactive slots
//    load row 0 (L1-hot) with c=0. unroll 4 -> 16 row loads in flight.
// ---------------------------------------------------------------------------
__global__ __launch_bounds__(256) void gather_ell(const uint2* __restrict__ esrcc,
                                                  const int* __restrict__ indeg,
                                                  const uint2* __restrict__ Xv,
                                                  uint2* __restrict__ A2) {
    __shared__ uint2 meta[8][N_REL][MAXDEG];   // {src, c_bits}, 8 KB
    int tid = threadIdx.x;
    int h   = tid >> 5;              // half-wave 0..7 -> node
    int l31 = tid & 31;
    int d   = blockIdx.x * 8 + h;    // grid = N_NODES/8 exactly

    int   n[N_REL];
    float rin[N_REL];
    int nm = 0;
#pragma unroll
    for (int r = 0; r < N_REL; r++) {
        int ind = indeg[r * N_NODES + d];
        n[r]   = ind > MAXDEG ? MAXDEG : ind;
        rin[r] = rsqrtf((float)(ind < 1 ? 1 : ind));
        nm = max(nm, n[r]);
        uint2 m = make_uint2(0u, 0u);
        if (l31 < n[r])
            m = esrcc[((size_t)r * N_NODES + d) * MAXDEG + l31];
        meta[h][r][l31] = m;
    }
    int nmax = max(nm, __shfl_xor(nm, 32));    // wave trip count (both nodes)
    __syncthreads();

    float4 acc[N_REL];
#pragma unroll
    for (int r = 0; r < N_REL; r++) acc[r] = make_float4(0.f, 0.f, 0.f, 0.f);

#pragma unroll 4
    for (int i = 0; i < nmax; i++) {
        uint2 m[N_REL];
#pragma unroll
        for (int r = 0; r < N_REL; r++) m[r] = meta[h][r][i];   // broadcast per half
        uint2 v[N_REL];
#pragma unroll
        for (int r = 0; r < N_REL; r++)
            v[r] = Xv[(size_t)m[r].x * (D / 4) + l31];           // 8B/lane, 2 rows/instr
#pragma unroll
        for (int r = 0; r < N_REL; r++) {
            union { unsigned u; float f; } cc; cc.u = m[r].y;
            union { unsigned u; float f; } a, b, e, g;
            a.u = v[r].x << 16; b.u = v[r].x & 0xFFFF0000u;
            e.u = v[r].y << 16; g.u = v[r].y & 0xFFFF0000u;
            acc[r].x += cc.f * a.f;
            acc[r].y += cc.f * b.f;
            acc[r].z += cc.f * e.f;
            acc[r].w += cc.f * g.f;
        }
    }

#pragma unroll
    for (int r = 0; r < N_REL; r++) {
        unsigned p0 = (unsigned)f2bf(rin[r] * acc[r].x) | ((unsigned)f2bf(rin[r] * acc[r].y) << 16);
        unsigned p1 = (unsigned)f2bf(rin[r] * acc[r].z) | ((unsigned)f2bf(rin[r] * acc[r].w) << 16);
        A2[(size_t)d * (KTOT / 4) + r * (D / 4) + l31] = make_uint2(p0, p1);
    }
}

// ---------------------------------------------------------------------------
// 4) Final GEMM: Z[100K][128] = A[100K][512](bf16) @ Wt^T via 16x16x32 MFMA.
//    A streamed linearly (latency-tolerant), Wt 128KB L2-hot. No LDS.
// ---------------------------------------------------------------------------
__global__ __launch_bounds__(256) void gemm_mfma(const unsigned short* __restrict__ A,
                                                 const unsigned short* __restrict__ Wt,
                                                 float* __restrict__ Z) {
    int w    = threadIdx.x >> 6;
    int lane = threadIdx.x & 63;
    int l15  = lane & 15;
    int quad = lane >> 4;
    int row0 = blockIdx.x * 128 + w * 32;

    f32x4 acc[2][8];
#pragma unroll
    for (int m = 0; m < 2; m++)
#pragma unroll
        for (int j = 0; j < 8; j++) acc[m][j] = (f32x4){0.f, 0.f, 0.f, 0.f};

    for (int k0 = 0; k0 < KTOT; k0 += 32) {
        bf16x8 a[2];
#pragma unroll
        for (int m = 0; m < 2; m++)
            a[m] = *(const bf16x8*)(A + (size_t)(row0 + m * 16 + l15) * KTOT + k0 + quad * 8);
#pragma unroll
        for (int j = 0; j < 8; j++) {
            bf16x8 b = *(const bf16x8*)(Wt + (size_t)(j * 16 + l15) * KTOT + k0 + quad * 8);
            acc[0][j] = __builtin_amdgcn_mfma_f32_16x16x32_bf16(a[0], b, acc[0][j], 0, 0, 0);
            acc[1][j] = __builtin_amdgcn_mfma_f32_16x16x32_bf16(a[1], b, acc[1][j], 0, 0, 0);
        }
    }

    // C/D layout: col = lane&15, row = quad*4 + reg
#pragma unroll
    for (int m = 0; m < 2; m++)
#pragma unroll
        for (int reg = 0; reg < 4; reg++) {
            int row = row0 + m * 16 + quad * 4 + reg;
            if (row < N_NODES) {
#pragma unroll
                for (int j = 0; j < 8; j++)
                    Z[(size_t)row * D + j * 16 + l15] = acc[m][j][reg];
            }
        }
}

// ---------------------------------------------------------------------------
extern "C" void kernel_launch(void* const* d_in, const int* in_sizes, int n_in,
                              void* d_out, int out_size, void* d_ws, size_t ws_size,
                              hipStream_t stream) {
    const int*   edges = (const int*)d_in[0];
    const float* X     = (const float*)d_in[1];
    const float* W     = (const float*)d_in[2];
    float*       Z     = (float*)d_out;

    auto align256 = [](size_t x) { return (x + 255) & ~(size_t)255; };
    char* ws = (char*)d_ws;
    size_t off = 0;
    int* gcur          = (int*)(ws + off);            off = align256(off + (size_t)2 * NKEY * 16 * sizeof(int));
    int* indeg         = (int*)(ws + off);            off = align256(off + (size_t)N_REL * N_NODES * sizeof(int));
    float* routf       = (float*)(ws + off);          off = align256(off + (size_t)N_REL * N_NODES * sizeof(float));
    uint2* esrcc       = (uint2*)(ws + off);          off = align256(off + (size_t)N_REL * N_NODES * MAXDEG * sizeof(uint2));
    unsigned short* Xb = (unsigned short*)(ws + off); off = align256(off + (size_t)N_NODES * D * sizeof(short));
    unsigned short* Wt = (unsigned short*)(ws + off); off = align256(off + (size_t)KTOT * D * sizeof(short));
    unsigned short* A  = (unsigned short*)(ws + off); off = align256(off + (size_t)M_PAD * KTOT * sizeof(short));
    // bucket arrays overlay A's region: dead before gather writes A.
    unsigned* bktd = (unsigned*)A;                                             // NKEY*CAP*4B = 11.5 MB
    unsigned* bkts = (unsigned*)((char*)A + (size_t)NKEY * CAP * sizeof(unsigned));  // +11.5 MB

    // only the 64 KB padded range-reservation counters need zeroing
    hipMemsetAsync(gcur, 0, (size_t)2 * NKEY * 16 * sizeof(int), stream);

    pass1<<<P1_BLKS + XC_BLKS + WC_BLKS, 256, 0, stream>>>(
        edges, gcur, bktd, bkts, X, Xb, W, Wt);

    pass2a<<<NKEY, 1024, 0, stream>>>(gcur, bkts, routf);

    pass2b<<<NKEY, 1024, 0, stream>>>(gcur, bktd, routf, esrcc, indeg);

    gather_ell<<<N_NODES / 8, 256, 0, stream>>>(
        esrcc, indeg, (const uint2*)Xb, (uint2*)A);

    gemm_mfma<<<M_PAD / 128, 256, 0, stream>>>(A, Wt, Z);
}